// Round 4
// baseline (660.628 us; speedup 1.0000x reference)
//
#include <hip/hip_runtime.h>

// SimpleGRU scan: B=2048 seqs, T=2048 steps, H=32, O=2, fp32.
// Round-4: split-K mapping done right. One batch per wave (2048 waves =
// 2 waves/SIMD -> cross-wave latency hiding; the machine has exactly 2
// recurrences per SIMD). Lane l = (j = l>>1 in [0,32), half = l&1): lane
// holds w_hh rows {j, 32+j, 64+j}, cols [16*half, 16*half+16) = 48 weights,
// asm-pinned (rounds 1-3 showed the backend otherwise sinks loads / spills
// to AGPR: VGPR_Count 68/48/80, ~200 cyc/step junk VALU). Split-K partner
// is lane^1 -> combine via DPP quad_perm(1,0,3,2) add: pure VALU, no LDS
// crossbar (round 2's xor-32 shfl added a serial LDS round-trip).
// Bias/x-gate seeds pre-scaled by (half==0) so the xor-combine counts them
// exactly once with zero per-step select cost.

__device__ __forceinline__ float sigmoid_fast(float s) {
    float e = __builtin_amdgcn_exp2f(s * -1.44269504088896340736f);
    return __builtin_amdgcn_rcpf(1.0f + e);
}

__device__ __forceinline__ float tanh_fast(float u) {
    // tanh(u) = 1 - 2/(1+exp2(2*log2e*u)); robust in fp32 at both tails
    float e = __builtin_amdgcn_exp2f(u * 2.88539008177792681472f);
    float r = __builtin_amdgcn_rcpf(1.0f + e);
    return fmaf(-2.0f, r, 1.0f);
}

// v + (v from partner lane l^1), via DPP quad_perm [1,0,3,2] (ctrl 0xB1).
__device__ __forceinline__ float xor1_add(float v) {
    int i = __float_as_int(v);
    int s = __builtin_amdgcn_update_dpp(i, i, 0xB1, 0xF, 0xF, true);
    return v + __int_as_float(s);
}

__global__ __launch_bounds__(64, 2)
void gru_scan_kernel(const float* __restrict__ x,      // [B,T]
                     const float* __restrict__ w_ih,   // [96,1]
                     const float* __restrict__ w_hh,   // [96,32]
                     const float* __restrict__ b_ih,   // [96]
                     const float* __restrict__ b_hh,   // [96]
                     const float* __restrict__ head_w, // [2,32]
                     const float* __restrict__ head_b, // [2]
                     float* __restrict__ out,          // [B,2]
                     int T)
{
    const int l    = (int)threadIdx.x;
    const int j    = l >> 1;    // hidden/gate index, 0..31
    const int half = l & 1;     // K-split half
    const int b    = (int)blockIdx.x;

    __shared__ __align__(16) float h_s[32];
    __shared__ __align__(16) float x_s[2][64];

    // ---- per-lane weights: 48 floats (3 gates x 16 k), asm-pinned ----
    float w[48];
    {
        const float4* wr4 = (const float4*)(w_hh + (     j) * 32 + half * 16);
        const float4* wz4 = (const float4*)(w_hh + (32 + j) * 32 + half * 16);
        const float4* wn4 = (const float4*)(w_hh + (64 + j) * 32 + half * 16);
#pragma unroll
        for (int q = 0; q < 4; ++q) {
            float4 a = wr4[q];
            w[     4*q+0]=a.x; w[     4*q+1]=a.y; w[     4*q+2]=a.z; w[     4*q+3]=a.w;
            float4 c = wz4[q];
            w[16 + 4*q+0]=c.x; w[16 + 4*q+1]=c.y; w[16 + 4*q+2]=c.z; w[16 + 4*q+3]=c.w;
            float4 d = wn4[q];
            w[32 + 4*q+0]=d.x; w[32 + 4*q+1]=d.y; w[32 + 4*q+2]=d.z; w[32 + 4*q+3]=d.w;
        }
    }
#pragma unroll
    for (int k = 0; k < 48; ++k) asm volatile("" : "+v"(w[k]));

    // seeds pre-scaled so only half 0 contributes bias + x-gate terms for
    // r/z and the bnh term for n (xor-combine then counts each once)
    const float hsel   = (half == 0) ? 1.0f : 0.0f;
    const float wihr_e = w_ih[j]      * hsel;
    const float wihz_e = w_ih[32 + j] * hsel;
    const float br_e   = (b_ih[j]      + b_hh[j])      * hsel;
    const float bz_e   = (b_ih[32 + j] + b_hh[32 + j]) * hsel;
    const float bnh_e  = b_hh[64 + j] * hsel;
    const float wihn   = w_ih[64 + j];   // needed in both halves (post-combine)
    const float bni    = b_ih[64 + j];

    const float* xrow   = x + (size_t)b * (size_t)T;
    const int    nchunk = T >> 6;   // 64-step chunks (T=2048 -> 32)

    float h = 0.0f;
    h_s[j] = 0.0f;                       // lanes 2j,2j+1 write same value: ok
    x_s[0][l] = xrow[l];
    float xnext = (nchunk > 1) ? xrow[64 + l] : 0.0f;
    __builtin_amdgcn_wave_barrier();

    const float4* h4 = (const float4*)(h_s + half * 16);

    for (int c = 0; c < nchunk; ++c) {
        const int buf = c & 1;
        const float* xs = &x_s[buf][0];
        for (int s4 = 0; s4 < 64; s4 += 4) {
            const float4 xq = *(const float4*)(xs + s4);  // uniform b128 bcast
#pragma unroll
            for (int s = 0; s < 4; ++s) {
                const float xv = (s == 0) ? xq.x : (s == 1) ? xq.y
                               : (s == 2) ? xq.z : xq.w;
                // h quads for this half (broadcast ds_read_b128, conflict-
                // free: even lanes banks 4q..4q+3, odd lanes 16+4q..19+4q)
                const float4 ha = h4[0], hb = h4[1], hc = h4[2], hd = h4[3];

                // 2 chains of 8 per gate
                float rA = fmaf(xv, wihr_e, br_e);
                float zA = fmaf(xv, wihz_e, bz_e);
                float nA = bnh_e;
                rA = fmaf(ha.x, w[ 0], rA); zA = fmaf(ha.x, w[16], zA); nA = fmaf(ha.x, w[32], nA);
                rA = fmaf(ha.y, w[ 1], rA); zA = fmaf(ha.y, w[17], zA); nA = fmaf(ha.y, w[33], nA);
                rA = fmaf(ha.z, w[ 2], rA); zA = fmaf(ha.z, w[18], zA); nA = fmaf(ha.z, w[34], nA);
                rA = fmaf(ha.w, w[ 3], rA); zA = fmaf(ha.w, w[19], zA); nA = fmaf(ha.w, w[35], nA);
                rA = fmaf(hb.x, w[ 4], rA); zA = fmaf(hb.x, w[20], zA); nA = fmaf(hb.x, w[36], nA);
                rA = fmaf(hb.y, w[ 5], rA); zA = fmaf(hb.y, w[21], zA); nA = fmaf(hb.y, w[37], nA);
                rA = fmaf(hb.z, w[ 6], rA); zA = fmaf(hb.z, w[22], zA); nA = fmaf(hb.z, w[38], nA);
                rA = fmaf(hb.w, w[ 7], rA); zA = fmaf(hb.w, w[23], zA); nA = fmaf(hb.w, w[39], nA);

                float rB = hc.x * w[ 8], zB = hc.x * w[24], nB = hc.x * w[40];
                rB = fmaf(hc.y, w[ 9], rB); zB = fmaf(hc.y, w[25], zB); nB = fmaf(hc.y, w[41], nB);
                rB = fmaf(hc.z, w[10], rB); zB = fmaf(hc.z, w[26], zB); nB = fmaf(hc.z, w[42], nB);
                rB = fmaf(hc.w, w[11], rB); zB = fmaf(hc.w, w[27], zB); nB = fmaf(hc.w, w[43], nB);
                rB = fmaf(hd.x, w[12], rB); zB = fmaf(hd.x, w[28], zB); nB = fmaf(hd.x, w[44], nB);
                rB = fmaf(hd.y, w[13], rB); zB = fmaf(hd.y, w[29], zB); nB = fmaf(hd.y, w[45], nB);
                rB = fmaf(hd.z, w[14], rB); zB = fmaf(hd.z, w[30], zB); nB = fmaf(hd.z, w[46], nB);
                rB = fmaf(hd.w, w[15], rB); zB = fmaf(hd.w, w[31], zB); nB = fmaf(hd.w, w[47], nB);

                // combine own halves, then partner lane via DPP xor-1 add
                const float rp = xor1_add(rA + rB);
                const float zp = xor1_add(zA + zB);
                const float np = xor1_add(nA + nB);

                const float r  = sigmoid_fast(rp);   // biases already inside
                const float z  = sigmoid_fast(zp);
                const float xn = fmaf(xv, wihn, bni);
                const float n  = tanh_fast(fmaf(r, np, xn));
                h = fmaf(z, h - n, n);               // (1-z)*n + z*h
                __builtin_amdgcn_wave_barrier();
                h_s[j] = h;                          // both half-lanes: same value
                __builtin_amdgcn_wave_barrier();     // in-order DS => RAW safe
            }
        }
        if (c + 1 < nchunk) {
            x_s[1 - buf][l] = xnext;                 // stage next chunk
            if (c + 2 < nchunk) xnext = xrow[(c + 2) * 64 + l];
            __builtin_amdgcn_wave_barrier();
        }
    }

    // ---- head: out[b,o] = head_b[o] + sum_k h[k]*head_w[o,k], o in {0,1} ----
    __builtin_amdgcn_wave_barrier();
    if (l < 2) {
        float acc = head_b[l];
        const float* hw = head_w + l * 32;
#pragma unroll
        for (int k = 0; k < 32; ++k) acc = fmaf(h_s[k], hw[k], acc);
        out[b * 2 + l] = acc;
    }
}

extern "C" void kernel_launch(void* const* d_in, const int* in_sizes, int n_in,
                              void* d_out, int out_size, void* d_ws, size_t ws_size,
                              hipStream_t stream) {
    const float* x      = (const float*)d_in[0];
    const float* w_ih   = (const float*)d_in[1];
    const float* w_hh   = (const float*)d_in[2];
    const float* b_ih   = (const float*)d_in[3];
    const float* b_hh   = (const float*)d_in[4];
    const float* head_w = (const float*)d_in[5];
    const float* head_b = (const float*)d_in[6];
    float* out = (float*)d_out;

    const int B = out_size / 2;          // O = 2
    const int T = in_sizes[0] / B;       // x is [B,T]

    dim3 grid(B), block(64);
    hipLaunchKernelGGL(gru_scan_kernel, grid, block, 0, stream,
                       x, w_ih, w_hh, b_ih, b_hh, head_w, head_b, out, T);
}

// Round 5
// 568.279 us; speedup vs baseline: 1.1625x; 1.1625x over previous
//
#include <hip/hip_runtime.h>

// SimpleGRU scan: B=2048 seqs, T=2048 steps, H=32, O=2, fp32 backbone.
// Round-5: round-4 structure (1 batch/wave, 2048 waves = 2 waves/SIMD,
// split-K lane pairs, DPP xor-1 combine) — which measured VALUBusy=86%
// (latency hidden, purely issue-bound) — with the gate matmul moved to
// v_dot2_f32_f16 (f16 pair inputs, fp32 accumulate):
//  * 24 fdot2 replace 48 fp32 FMAs per wave-step (2 MACs/instr)
//  * per-lane weights: 48 f16 in 24 packed VGPRs (held as ints, bit-cast
//    at use) — small enough that the allocator's AGPR-spill behavior
//    (rounds 2-4: ~2cyc/weight/step junk tax, VGPR_Count 48-80) can't bite
//  * h published to LDS as f16 (1 cvt + ds_write_b16); each half reads its
//    16 h values as 2x ds_read_b128 broadcast (conflict-free)
// Recurrence backbone (h, z*h update, x gates, activations) stays fp32;
// f16 only enters the h.W_hh products -> est. added error ~2-5e-4, well
// under the 3.5e-3 threshold (fp32 version measured 4.9e-4).

typedef _Float16 f16x2 __attribute__((ext_vector_type(2)));

__device__ __forceinline__ float sigmoid_fast(float s) {
    float e = __builtin_amdgcn_exp2f(s * -1.44269504088896340736f);
    return __builtin_amdgcn_rcpf(1.0f + e);
}

__device__ __forceinline__ float tanh_fast(float u) {
    // tanh(u) = 1 - 2/(1+exp2(2*log2e*u)); robust in fp32 at both tails
    float e = __builtin_amdgcn_exp2f(u * 2.88539008177792681472f);
    float r = __builtin_amdgcn_rcpf(1.0f + e);
    return fmaf(-2.0f, r, 1.0f);
}

// v + (v from partner lane l^1), via DPP quad_perm [1,0,3,2] (ctrl 0xB1).
__device__ __forceinline__ float xor1_add(float v) {
    int i = __float_as_int(v);
    int s = __builtin_amdgcn_update_dpp(i, i, 0xB1, 0xF, 0xF, true);
    return v + __int_as_float(s);
}

__device__ __forceinline__ float fdot2(int a, int b, float c) {
    return __builtin_amdgcn_fdot2(__builtin_bit_cast(f16x2, a),
                                  __builtin_bit_cast(f16x2, b), c, false);
}

__device__ __forceinline__ int pack_pair(float a, float b) {
    f16x2 p;
    p.x = (_Float16)a;
    p.y = (_Float16)b;
    return __builtin_bit_cast(int, p);
}

__global__ __launch_bounds__(64, 2)
void gru_scan_kernel(const float* __restrict__ x,      // [B,T]
                     const float* __restrict__ w_ih,   // [96,1]
                     const float* __restrict__ w_hh,   // [96,32]
                     const float* __restrict__ b_ih,   // [96]
                     const float* __restrict__ b_hh,   // [96]
                     const float* __restrict__ head_w, // [2,32]
                     const float* __restrict__ head_b, // [2]
                     float* __restrict__ out,          // [B,2]
                     int T)
{
    const int l    = (int)threadIdx.x;
    const int j    = l >> 1;    // hidden/gate index, 0..31
    const int half = l & 1;     // K-split half
    const int b    = (int)blockIdx.x;

    __shared__ __align__(16) _Float16 h16[32];   // f16 h for gate matmul
    __shared__ __align__(16) float    hf_s[32];  // fp32 h for head epilogue
    __shared__ __align__(16) float    x_s[2][64];

    // ---- per-lane weights: 48 f16 packed into 24 int regs, asm-pinned ----
    int wR[8], wZ[8], wN[8];
    {
        const float* pR = w_hh + (     j) * 32 + half * 16;
        const float* pZ = w_hh + (32 + j) * 32 + half * 16;
        const float* pN = w_hh + (64 + j) * 32 + half * 16;
#pragma unroll
        for (int q = 0; q < 8; ++q) {
            wR[q] = pack_pair(pR[2*q], pR[2*q+1]);
            wZ[q] = pack_pair(pZ[2*q], pZ[2*q+1]);
            wN[q] = pack_pair(pN[2*q], pN[2*q+1]);
        }
    }
#pragma unroll
    for (int q = 0; q < 8; ++q) {
        asm volatile("" : "+v"(wR[q]), "+v"(wZ[q]), "+v"(wN[q]));
    }

    // seeds pre-scaled so only half 0 contributes bias + x-gate terms for
    // r/z and the bnh term for n (xor-combine then counts each once)
    const float hsel   = (half == 0) ? 1.0f : 0.0f;
    const float wihr_e = w_ih[j]      * hsel;
    const float wihz_e = w_ih[32 + j] * hsel;
    const float br_e   = (b_ih[j]      + b_hh[j])      * hsel;
    const float bz_e   = (b_ih[32 + j] + b_hh[32 + j]) * hsel;
    const float bnh_e  = b_hh[64 + j] * hsel;
    const float wihn   = w_ih[64 + j];   // post-combine, both halves
    const float bni    = b_ih[64 + j];

    const float* xrow   = x + (size_t)b * (size_t)T;
    const int    nchunk = T >> 6;   // 64-step chunks (T=2048 -> 32)

    float h = 0.0f;
    if (l < 32) h16[l] = (_Float16)0.0f;
    x_s[0][l] = xrow[l];
    float xnext = (nchunk > 1) ? xrow[64 + l] : 0.0f;
    __builtin_amdgcn_wave_barrier();

    // this half's 16 h values = 32 bytes = 2 x b128 broadcast reads
    const int4* hq = (const int4*)(h16 + half * 16);

    for (int c = 0; c < nchunk; ++c) {
        const int buf = c & 1;
        const float* xs = &x_s[buf][0];
        for (int s4 = 0; s4 < 64; s4 += 4) {
            const float4 xq = *(const float4*)(xs + s4);  // uniform b128
#pragma unroll
            for (int s = 0; s < 4; ++s) {
                const float xv = (s == 0) ? xq.x : (s == 1) ? xq.y
                               : (s == 2) ? xq.z : xq.w;
                const int4 H0 = hq[0];   // h pairs 0..3 (f16x2 as int)
                const int4 H1 = hq[1];   // h pairs 4..7

                // 2 chains of 4 fdot2 per gate (8 pairs = 16 MACs)
                float rA = fdot2(H0.x, wR[0], fmaf(xv, wihr_e, br_e));
                float zA = fdot2(H0.x, wZ[0], fmaf(xv, wihz_e, bz_e));
                float nA = fdot2(H0.x, wN[0], bnh_e);
                rA = fdot2(H0.y, wR[1], rA); zA = fdot2(H0.y, wZ[1], zA); nA = fdot2(H0.y, wN[1], nA);
                rA = fdot2(H0.z, wR[2], rA); zA = fdot2(H0.z, wZ[2], zA); nA = fdot2(H0.z, wN[2], nA);
                rA = fdot2(H0.w, wR[3], rA); zA = fdot2(H0.w, wZ[3], zA); nA = fdot2(H0.w, wN[3], nA);

                float rB = fdot2(H1.x, wR[4], 0.0f);
                float zB = fdot2(H1.x, wZ[4], 0.0f);
                float nB = fdot2(H1.x, wN[4], 0.0f);
                rB = fdot2(H1.y, wR[5], rB); zB = fdot2(H1.y, wZ[5], zB); nB = fdot2(H1.y, wN[5], nB);
                rB = fdot2(H1.z, wR[6], rB); zB = fdot2(H1.z, wZ[6], zB); nB = fdot2(H1.z, wN[6], nB);
                rB = fdot2(H1.w, wR[7], rB); zB = fdot2(H1.w, wZ[7], zB); nB = fdot2(H1.w, wN[7], nB);

                // combine own halves, then partner lane via DPP xor-1 add
                const float rp = xor1_add(rA + rB);
                const float zp = xor1_add(zA + zB);
                const float np = xor1_add(nA + nB);

                const float r  = sigmoid_fast(rp);   // biases already inside
                const float z  = sigmoid_fast(zp);
                const float xn = fmaf(xv, wihn, bni);
                const float n  = tanh_fast(fmaf(r, np, xn));
                h = fmaf(z, h - n, n);               // (1-z)*n + z*h
                __builtin_amdgcn_wave_barrier();
                h16[j] = (_Float16)h;                // both half-lanes: same val
                __builtin_amdgcn_wave_barrier();     // in-order DS => RAW safe
            }
        }
        if (c + 1 < nchunk) {
            x_s[1 - buf][l] = xnext;                 // stage next chunk
            if (c + 2 < nchunk) xnext = xrow[(c + 2) * 64 + l];
            __builtin_amdgcn_wave_barrier();
        }
    }

    // ---- head: out[b,o] = head_b[o] + sum_k h[k]*head_w[o,k] (fp32 h) ----
    hf_s[j] = h;                                     // both half-lanes: same val
    __builtin_amdgcn_wave_barrier();
    if (l < 2) {
        float acc = head_b[l];
        const float* hw = head_w + l * 32;
#pragma unroll
        for (int k = 0; k < 32; ++k) acc = fmaf(hf_s[k], hw[k], acc);
        out[b * 2 + l] = acc;
    }
}

extern "C" void kernel_launch(void* const* d_in, const int* in_sizes, int n_in,
                              void* d_out, int out_size, void* d_ws, size_t ws_size,
                              hipStream_t stream) {
    const float* x      = (const float*)d_in[0];
    const float* w_ih   = (const float*)d_in[1];
    const float* w_hh   = (const float*)d_in[2];
    const float* b_ih   = (const float*)d_in[3];
    const float* b_hh   = (const float*)d_in[4];
    const float* head_w = (const float*)d_in[5];
    const float* head_b = (const float*)d_in[6];
    float* out = (float*)d_out;

    const int B = out_size / 2;          // O = 2
    const int T = in_sizes[0] / B;       // x is [B,T]

    dim3 grid(B), block(64);
    hipLaunchKernelGGL(gru_scan_kernel, grid, block, 0, stream,
                       x, w_ih, w_hh, b_ih, b_hh, head_w, head_b, out, T);
}